// Round 1
// baseline (204.068 us; speedup 1.0000x reference)
//
#include <hip/hip_runtime.h>
#include <cfloat>

// ---- problem constants (fixed by setup_inputs) ----
constexpr int A_TOT = 21504;      // 128^2 + 64^2 + 32^2
constexpr int NB    = 8;
constexpr int NG    = 20;
constexpr int HW_M  = 1 << 20;    // 1024*1024

// ---- workspace layout (float offsets) ----
constexpr size_t OFF_DEC  = 0;
constexpr size_t SZ_DEC   = (size_t)NB * A_TOT * 8;            // 1,376,256
constexpr size_t OFF_IOUS = OFF_DEC + SZ_DEC;
constexpr size_t SZ_GA    = (size_t)NB * NG * A_TOT;           // 3,440,640
constexpr size_t OFF_COST = OFF_IOUS + SZ_GA;
constexpr size_t OFF_THRC = OFF_COST + SZ_GA;                  // NB*NG floats
constexpr size_t OFF_THRI = OFF_THRC + NB * NG;                // NB*NG ints
constexpr size_t OFF_CAND = OFF_THRI + NB * NG;                // NB*A_TOT bytes
constexpr size_t OFF_PM   = OFF_CAND + (NB * A_TOT) / 4;       // 672*4 floats
constexpr size_t OFF_PK   = OFF_PM + 672 * 4;                  // 1024*10 floats
// total ≈ 8,313,792 floats ≈ 33.3 MB

__device__ __forceinline__ float sigf(float x) { return 1.f / (1.f + expf(-x)); }
__device__ __forceinline__ float bcef(float x, float y) {
  return fmaxf(x, 0.f) - x * y + log1pf(expf(-fabsf(x)));
}
__device__ __forceinline__ void anchor_geom(int a, int& hw, int& lw, float& st) {
  if (a < 16384)      { hw = a;         lw = 7; st = 8.f;  }
  else if (a < 20480) { hw = a - 16384; lw = 6; st = 16.f; }
  else                { hw = a - 20480; lw = 5; st = 32.f; }
}

// ---------------- decode: p3/p4/p5 -> dec[B][A][8] ----------------
__global__ __launch_bounds__(256) void k_decode(
    const float* __restrict__ p3, const float* __restrict__ p4,
    const float* __restrict__ p5, float* __restrict__ dec) {
  int a = blockIdx.x * 256 + threadIdx.x;
  int b = blockIdx.y;
  int hw, lw; float st;
  anchor_geom(a, hw, lw, st);
  const float* src; int HW;
  if (a < 16384)      { src = p3; HW = 16384; }
  else if (a < 20480) { src = p4; HW = 4096;  }
  else                { src = p5; HW = 1024;  }
  int x = hw & ((1 << lw) - 1), y = hw >> lw;
  const float* c0 = src + (size_t)b * 8 * HW + hw;
  float o0 = c0[0];
  float o1 = c0[(size_t)HW];
  float o2 = c0[(size_t)2 * HW];
  float o3 = c0[(size_t)3 * HW];
  float o4 = c0[(size_t)4 * HW];
  float o5 = c0[(size_t)5 * HW];
  float o6 = c0[(size_t)6 * HW];
  float o7 = c0[(size_t)7 * HW];
  float4 d0 = make_float4((o0 + (float)x) * st, (o1 + (float)y) * st,
                          expf(o2) * st, expf(o3) * st);
  float4 d1 = make_float4(o4, o5, o6, o7);
  float4* dst = (float4*)(dec + ((size_t)b * A_TOT + a) * 8);
  dst[0] = d0; dst[1] = d1;
}

// -------- cost/iou/cand: per-(b,a) thread loops 20 gts --------
__global__ __launch_bounds__(256) void k_cost(
    const float* __restrict__ dec, const float* __restrict__ labels,
    float* __restrict__ ious, float* __restrict__ cost,
    unsigned char* __restrict__ cand) {
  __shared__ float gt[NG][5];
  int tid = threadIdx.x, b = blockIdx.y;
  if (tid < NG * 5) ((float*)gt)[tid] = labels[b * NG * 5 + tid];
  __syncthreads();
  int a = blockIdx.x * 256 + tid;

  const float4* dp = (const float4*)(dec + ((size_t)b * A_TOT + a) * 8);
  float4 d0 = dp[0], d1 = dp[1];
  float px = d0.x, py = d0.y, pw = d0.z, ph = d0.w;

  int hw, lw; float st;
  anchor_geom(a, hw, lw, st);
  int x = hw & ((1 << lw) - 1), y = hw >> lw;
  float xc = ((float)x + 0.5f) * st, yc = ((float)y + 0.5f) * st;

  // per-anchor class-cost pieces: cls_cost(g) = -(cc[cg] + S)
  float so = sigf(d1.x);
  float cc0, cc1, cc2, S;
  {
    float p0 = sqrtf(sigf(d1.y) * so);
    float p1 = sqrtf(sigf(d1.z) * so);
    float p2 = sqrtf(sigf(d1.w) * so);
    float lg0 = logf(p0 + 1e-8f), lg1 = logf(p1 + 1e-8f), lg2 = logf(p2 + 1e-8f);
    float m0 = logf(1.f - p0 + 1e-8f), m1 = logf(1.f - p1 + 1e-8f), m2 = logf(1.f - p2 + 1e-8f);
    S = m0 + m1 + m2;
    cc0 = lg0 - m0; cc1 = lg1 - m1; cc2 = lg2 - m2;
  }

  float iouv[NG];
  unsigned bothMask = 0;
  bool anyBox = false, anyCtr = false;
  float hpw = pw * 0.5f, hph = ph * 0.5f;
  float plx = px - hpw, prx = px + hpw, pty = py - hph, pby = py + hph;
  float parea = pw * ph;
  float r = 2.5f * st;

#pragma unroll
  for (int g = 0; g < NG; ++g) {
    float gx = gt[g][0], gy = gt[g][1], gw = gt[g][2], gh = gt[g][3];
    float hgw = gw * 0.5f, hgh = gh * 0.5f;
    float glx = gx - hgw, grx = gx + hgw, gty = gy - hgh, gby = gy + hgh;
    bool ib = (xc > glx) && (xc < grx) && (yc > gty) && (yc < gby);
    bool ic = (xc > gx - r) && (xc < gx + r) && (yc > gy - r) && (yc < gy + r);
    anyBox |= ib; anyCtr |= ic;
    if (ib && ic) bothMask |= (1u << g);
    float tlx = fmaxf(glx, plx), brx = fminf(grx, prx);
    float tly = fmaxf(gty, pty), bry = fminf(gby, pby);
    float en = ((tlx < brx) && (tly < bry)) ? 1.f : 0.f;
    float ai = (brx - tlx) * (bry - tly) * en;
    float au = gw * gh + parea - ai;
    iouv[g] = ai / (au + 1e-16f);
  }
  bool cd = anyBox || anyCtr;
  cand[(size_t)b * A_TOT + a] = cd ? 1 : 0;

#pragma unroll
  for (int g = 0; g < NG; ++g) {
    float iv = cd ? iouv[g] : 0.f;
    int cg = (int)gt[g][4];
    float ccg = (cg == 0) ? cc0 : ((cg == 1) ? cc1 : cc2);
    float c = -(ccg + S) - 3.f * logf(iv + 1e-8f) +
              (((bothMask >> g) & 1u) ? 0.f : 100000.f);
    size_t idx = ((size_t)(b * NG + g)) * A_TOT + a;
    ious[idx] = iv;
    cost[idx] = cd ? c : 1e9f;
  }
}

// -------- per-(b,g): dyn_k from top-10 ious; dyn_k-th smallest (cost,idx) --------
__global__ __launch_bounds__(256) void k_topk(
    const float* __restrict__ ious, const float* __restrict__ cost,
    float* __restrict__ thrC, int* __restrict__ thrI) {
  int g = blockIdx.x, b = blockIdx.y, tid = threadIdx.x;
  const float* iouRow  = ious + ((size_t)(b * NG + g)) * A_TOT;
  const float* costRow = cost + ((size_t)(b * NG + g)) * A_TOT;
  __shared__ float sV[256][11];
  __shared__ float sC[256][11];
  __shared__ int   sI[256][11];

  // phase 1: per-thread top-10 iou (values only; sum is order-invariant)
  float tv[10];
#pragma unroll
  for (int j = 0; j < 10; ++j) tv[j] = -1e30f;
  for (int i = tid; i < A_TOT; i += 256) {
    float v = iouRow[i];
#pragma unroll
    for (int j = 0; j < 10; ++j)
      if (v > tv[j]) { float t = tv[j]; tv[j] = v; v = t; }
  }
#pragma unroll
  for (int j = 0; j < 10; ++j) sV[tid][j] = tv[j];
  sV[tid][10] = -1e30f;
  __syncthreads();
  for (int half = 128; half >= 1; half >>= 1) {
    if (tid < half) {
      const float* Ar = sV[tid];
      const float* Br = sV[tid + half];
      float out[10]; int pa = 0, pb = 0;
#pragma unroll
      for (int j = 0; j < 10; ++j) {
        float av = Ar[pa], bv = Br[pb];
        bool ta = (av >= bv);
        out[j] = ta ? av : bv;
        pa += ta ? 1 : 0; pb += ta ? 0 : 1;
      }
#pragma unroll
      for (int j = 0; j < 10; ++j) sV[tid][j] = out[j];
    }
    __syncthreads();
  }

  // phase 2: per-thread bottom-10 (cost, idx) lexicographic (stable-sort ties)
  float tc[10]; int ti[10];
#pragma unroll
  for (int j = 0; j < 10; ++j) { tc[j] = FLT_MAX; ti[j] = 0x7fffffff; }
  for (int i = tid; i < A_TOT; i += 256) {
    float c = costRow[i]; int ii = i;
#pragma unroll
    for (int j = 0; j < 10; ++j) {
      bool lt = (c < tc[j]) || (c == tc[j] && ii < ti[j]);
      if (lt) {
        float t = tc[j]; tc[j] = c; c = t;
        int t2 = ti[j]; ti[j] = ii; ii = t2;
      }
    }
  }
#pragma unroll
  for (int j = 0; j < 10; ++j) { sC[tid][j] = tc[j]; sI[tid][j] = ti[j]; }
  sC[tid][10] = FLT_MAX; sI[tid][10] = 0x7fffffff;
  __syncthreads();
  for (int half = 128; half >= 1; half >>= 1) {
    if (tid < half) {
      const float* Ac = sC[tid]; const float* Bc = sC[tid + half];
      const int*   Ai = sI[tid]; const int*   Bi = sI[tid + half];
      float oc[10]; int oi[10]; int pa = 0, pb = 0;
#pragma unroll
      for (int j = 0; j < 10; ++j) {
        float ac = Ac[pa], bc = Bc[pb];
        int ai_ = Ai[pa], bi_ = Bi[pb];
        bool ta = (ac < bc) || (ac == bc && ai_ < bi_);
        oc[j] = ta ? ac : bc; oi[j] = ta ? ai_ : bi_;
        pa += ta ? 1 : 0; pb += ta ? 0 : 1;
      }
#pragma unroll
      for (int j = 0; j < 10; ++j) { sC[tid][j] = oc[j]; sI[tid][j] = oi[j]; }
    }
    __syncthreads();
  }

  if (tid == 0) {
    float s = 0.f;
#pragma unroll
    for (int j = 0; j < 10; ++j) s += sV[0][j];
    int k = (int)s; if (k < 1) k = 1;     // dyn_k in [1,10]
    thrC[b * NG + g] = sC[0][k - 1];
    thrI[b * NG + g] = sI[0][k - 1];
  }
}

// -------- matching resolution + detection loss partials --------
__global__ __launch_bounds__(256) void k_match(
    const float* __restrict__ dec, const float* __restrict__ labels,
    const float* __restrict__ ious, const float* __restrict__ cost,
    const unsigned char* __restrict__ cand,
    const float* __restrict__ thrC, const int* __restrict__ thrI,
    float* __restrict__ pm) {
  __shared__ float gt[NG][5];
  __shared__ float tC[NG];
  __shared__ int   tI[NG];
  int tid = threadIdx.x, b = blockIdx.y;
  if (tid < NG * 5) ((float*)gt)[tid] = labels[b * NG * 5 + tid];
  if (tid >= 128 && tid < 128 + NG) tC[tid - 128] = thrC[b * NG + tid - 128];
  if (tid >= 160 && tid < 160 + NG) tI[tid - 160] = thrI[b * NG + tid - 160];
  __syncthreads();
  int a = blockIdx.x * 256 + tid;

  bool cd = cand[(size_t)b * A_TOT + a] != 0;
  int cnt = 0, firstg = -1, gmin = 0;
  float minc = FLT_MAX, pisum = 0.f, iou_gmin = 0.f;
#pragma unroll
  for (int g = 0; g < NG; ++g) {
    size_t idx = ((size_t)(b * NG + g)) * A_TOT + a;
    float c = cost[idx];
    float iv = ious[idx];
    if (c < minc) { minc = c; gmin = g; iou_gmin = iv; }   // first-argmin
    bool m = cd && ((c < tC[g]) || (c == tC[g] && a <= tI[g]));
    if (m) { cnt++; if (firstg < 0) firstg = g; pisum += iv; }
  }
  if (cnt > 1) { firstg = gmin; pisum = iou_gmin; }  // multi -> best only
  bool fg = cnt > 0;

  const float4* dp = (const float4*)(dec + ((size_t)b * A_TOT + a) * 8);
  float4 d0 = dp[0], d1 = dp[1];
  float l_obj = bcef(d1.x, fg ? 1.f : 0.f);
  float l_iou = 0.f, l_cls = 0.f, nfg = fg ? 1.f : 0.f;
  if (fg) {
    float gx = gt[firstg][0], gy = gt[firstg][1];
    float gw = gt[firstg][2], gh = gt[firstg][3];
    int cg = (int)gt[firstg][4];
    float px = d0.x, py = d0.y, pw = d0.z, ph = d0.w;
    float tlx = fmaxf(px - pw * 0.5f, gx - gw * 0.5f);
    float brx = fminf(px + pw * 0.5f, gx + gw * 0.5f);
    float tly = fmaxf(py - ph * 0.5f, gy - gh * 0.5f);
    float bry = fminf(py + ph * 0.5f, gy + gh * 0.5f);
    float en = ((tlx < brx) && (tly < bry)) ? 1.f : 0.f;
    float ai = (brx - tlx) * (bry - tly) * en;
    float au = pw * ph + gw * gh - ai;
    float iou = ai / (au + 1e-16f);
    l_iou = 1.f - iou * iou;
    l_cls  = bcef(d1.y, (cg == 0) ? pisum : 0.f);
    l_cls += bcef(d1.z, (cg == 1) ? pisum : 0.f);
    l_cls += bcef(d1.w, (cg == 2) ? pisum : 0.f);
  }

  // block-reduce 4 values -> per-block partials (deterministic, no atomics)
  __shared__ float scr[4][4];
  float vals[4] = { nfg, l_iou, l_obj, l_cls };
#pragma unroll
  for (int k = 0; k < 4; ++k) {
    float v = vals[k];
#pragma unroll
    for (int off = 32; off > 0; off >>= 1) v += __shfl_down(v, off, 64);
    if ((tid & 63) == 0) scr[tid >> 6][k] = v;
  }
  __syncthreads();
  if (tid == 0) {
    int bf = blockIdx.y * gridDim.x + blockIdx.x;
#pragma unroll
    for (int k = 0; k < 4; ++k)
      pm[(size_t)bf * 4 + k] = scr[0][k] + scr[1][k] + scr[2][k] + scr[3][k];
  }
}

// -------- mask loss: fused log-softmax CE + dice stats --------
__global__ __launch_bounds__(256) void k_mask(
    const float* __restrict__ mi, const int* __restrict__ ml,
    float* __restrict__ pk) {
  constexpr long long N4 = ((long long)NB * HW_M) / 4;
  float ce = 0.f, tp0 = 0, tp1 = 0, tp2 = 0;
  float ss0 = 0, ss1 = 0, ss2 = 0, c0 = 0, c1 = 0, c2 = 0;

  auto proc = [&](float v0, float v1, float v2, int l) {
    float m = fmaxf(v0, fmaxf(v1, v2));
    float e0 = expf(v0 - m), e1 = expf(v1 - m), e2 = expf(v2 - m);
    float sum = e0 + e1 + e2;
    float lse = m + logf(sum);
    float inv = 1.f / sum;
    float s0 = e0 * inv, s1 = e1 * inv, s2 = e2 * inv;
    ss0 += s0; ss1 += s1; ss2 += s2;
    if (l == 0)      { ce += v0 - lse; tp0 += s0; c0 += 1.f; }
    else if (l == 1) { ce += v1 - lse; tp1 += s1; c1 += 1.f; }
    else             { ce += v2 - lse; tp2 += s2; c2 += 1.f; }
  };

  long long stride = (long long)gridDim.x * blockDim.x;
  for (long long i4 = (long long)blockIdx.x * blockDim.x + threadIdx.x;
       i4 < N4; i4 += stride) {
    long long i = i4 * 4;
    int b  = (int)(i >> 20);
    int hw = (int)(i & (HW_M - 1));
    const float* base = mi + (size_t)b * 3 * HW_M + hw;
    float4 x0 = *(const float4*)(base);
    float4 x1 = *(const float4*)(base + HW_M);
    float4 x2 = *(const float4*)(base + 2 * HW_M);
    int4 lb = *(const int4*)(ml + i);
    proc(x0.x, x1.x, x2.x, lb.x);
    proc(x0.y, x1.y, x2.y, lb.y);
    proc(x0.z, x1.z, x2.z, lb.z);
    proc(x0.w, x1.w, x2.w, lb.w);
  }

  __shared__ float scr[4][10];
  float vals[10] = { ce, tp0, tp1, tp2, ss0, ss1, ss2, c0, c1, c2 };
#pragma unroll
  for (int k = 0; k < 10; ++k) {
    float v = vals[k];
#pragma unroll
    for (int off = 32; off > 0; off >>= 1) v += __shfl_down(v, off, 64);
    if ((threadIdx.x & 63) == 0) scr[threadIdx.x >> 6][k] = v;
  }
  __syncthreads();
  if (threadIdx.x == 0) {
#pragma unroll
    for (int k = 0; k < 10; ++k)
      pk[(size_t)blockIdx.x * 10 + k] = scr[0][k] + scr[1][k] + scr[2][k] + scr[3][k];
  }
}

// -------- final reduce + output --------
__device__ __forceinline__ float bsum256(float v, float* scr) {
#pragma unroll
  for (int off = 32; off > 0; off >>= 1) v += __shfl_down(v, off, 64);
  __syncthreads();
  if ((threadIdx.x & 63) == 0) scr[threadIdx.x >> 6] = v;
  __syncthreads();
  return scr[0] + scr[1] + scr[2] + scr[3];
}

__global__ __launch_bounds__(256) void k_final(
    const float* __restrict__ pm, const float* __restrict__ pk,
    float* __restrict__ out) {
  __shared__ float scr[4];
  int tid = threadIdx.x;
  float t0 = 0, t1 = 0, t2 = 0, t3 = 0;
  for (int r = tid; r < 672; r += 256) {
    t0 += pm[(size_t)r * 4 + 0];
    t1 += pm[(size_t)r * 4 + 1];
    t2 += pm[(size_t)r * 4 + 2];
    t3 += pm[(size_t)r * 4 + 3];
  }
  float u[10] = {0,0,0,0,0,0,0,0,0,0};
  for (int r = tid; r < 1024; r += 256) {
#pragma unroll
    for (int k = 0; k < 10; ++k) u[k] += pk[(size_t)r * 10 + k];
  }
  float S_nfg = bsum256(t0, scr);
  float S_iou = bsum256(t1, scr);
  float S_obj = bsum256(t2, scr);
  float S_cls = bsum256(t3, scr);
  float S_ce  = bsum256(u[0], scr);
  float S_tp0 = bsum256(u[1], scr);
  float S_tp1 = bsum256(u[2], scr);
  float S_tp2 = bsum256(u[3], scr);
  float S_ss0 = bsum256(u[4], scr);
  float S_ss1 = bsum256(u[5], scr);
  float S_ss2 = bsum256(u[6], scr);
  float S_c0  = bsum256(u[7], scr);
  float S_c1  = bsum256(u[8], scr);
  float S_c2  = bsum256(u[9], scr);

  if (tid == 0) {
    float nfg = fmaxf(S_nfg, 1.f);
    float o1 = 5.f * S_iou / nfg;
    float o2 = S_obj / nfg;
    float o3 = S_cls / nfg;
    float ce = -S_ce / (float)((long long)NB << 20);
    float tps[3] = { S_tp0, S_tp1, S_tp2 };
    float sss[3] = { S_ss0, S_ss1, S_ss2 };
    float cns[3] = { S_c0, S_c1, S_c2 };
    float ds = 0.f;
#pragma unroll
    for (int c = 0; c < 3; ++c) {
      float tp = tps[c];
      float fp = sss[c] - tp;
      float fn = cns[c] - tp;
      ds += (2.f * tp + 1e-5f) / (2.f * tp + fn + fp + 1e-5f);
    }
    float dice = 1.f - ds / 3.f;
    float o4 = ce + dice;
    out[0] = o1 + o2 + o3 + o4;
    out[1] = o1;
    out[2] = o2;
    out[3] = o3;
    out[4] = o4;
    out[5] = 0.f;
  }
}

extern "C" void kernel_launch(void* const* d_in, const int* in_sizes, int n_in,
                              void* d_out, int out_size, void* d_ws, size_t ws_size,
                              hipStream_t stream) {
  const float* p3     = (const float*)d_in[0];
  const float* p4     = (const float*)d_in[1];
  const float* p5     = (const float*)d_in[2];
  const float* mi     = (const float*)d_in[3];
  const float* labels = (const float*)d_in[4];
  // d_in[5] input_images: unused by the loss
  const int*   ml     = (const int*)d_in[6];
  // d_in[7] now_epoch: unused

  float* ws   = (float*)d_ws;
  float* dec  = ws + OFF_DEC;
  float* ious = ws + OFF_IOUS;
  float* cost = ws + OFF_COST;
  float* thrC = ws + OFF_THRC;
  int*   thrI = (int*)(ws + OFF_THRI);
  unsigned char* cand = (unsigned char*)(ws + OFF_CAND);
  float* pm   = ws + OFF_PM;
  float* pk   = ws + OFF_PK;
  float* out  = (float*)d_out;

  dim3 gA(A_TOT / 256, NB);   // 21504 = 84*256 exactly
  k_decode<<<gA, 256, 0, stream>>>(p3, p4, p5, dec);
  k_cost<<<gA, 256, 0, stream>>>(dec, labels, ious, cost, cand);
  k_topk<<<dim3(NG, NB), 256, 0, stream>>>(ious, cost, thrC, thrI);
  k_match<<<gA, 256, 0, stream>>>(dec, labels, ious, cost, cand, thrC, thrI, pm);
  k_mask<<<1024, 256, 0, stream>>>(mi, ml, pk);
  k_final<<<1, 256, 0, stream>>>(pm, pk, out);
}

// Round 2
// 144.088 us; speedup vs baseline: 1.4163x; 1.4163x over previous
//
#include <hip/hip_runtime.h>
#include <cfloat>

// ---- problem constants (fixed by setup_inputs) ----
constexpr int A_TOT = 21504;      // 128^2 + 64^2 + 32^2
constexpr int NB    = 8;
constexpr int NG    = 20;
constexpr int HW_M  = 1 << 20;    // 1024*1024
constexpr int SPLIT = 8;          // chunks per (b,g) row for top-k
constexpr int CHUNK = A_TOT / SPLIT;   // 2688

// ---- workspace layout (float offsets) ----
constexpr size_t OFF_DEC  = 0;
constexpr size_t SZ_DEC   = (size_t)NB * A_TOT * 8;            // 1,376,256
constexpr size_t OFF_IOUS = OFF_DEC + SZ_DEC;
constexpr size_t SZ_GA    = (size_t)NB * NG * A_TOT;           // 3,440,640
constexpr size_t OFF_COST = OFF_IOUS + SZ_GA;
constexpr size_t OFF_THRC = OFF_COST + SZ_GA;                  // NB*NG floats
constexpr size_t OFF_THRI = OFF_THRC + NB * NG;                // NB*NG ints
constexpr size_t OFF_CAND = OFF_THRI + NB * NG;                // NB*A_TOT bytes
constexpr size_t OFF_PM   = OFF_CAND + (NB * A_TOT) / 4;       // 672*4 floats
constexpr size_t OFF_PK   = OFF_PM + 672 * 4;                  // 1024*10 floats
constexpr size_t OFF_PV   = OFF_PK + 1024 * 10;                // part iou vals
constexpr size_t SZ_PART  = (size_t)NB * NG * SPLIT * 10;      // 12,800
constexpr size_t OFF_PC   = OFF_PV + SZ_PART;                  // part costs
constexpr size_t OFF_PI   = OFF_PC + SZ_PART;                  // part idx (int)
// total ≈ 8.35M floats ≈ 33.4 MB

__device__ __forceinline__ float sigf(float x) { return 1.f / (1.f + expf(-x)); }
__device__ __forceinline__ float bcef(float x, float y) {
  return fmaxf(x, 0.f) - x * y + log1pf(expf(-fabsf(x)));
}
__device__ __forceinline__ void anchor_geom(int a, int& hw, int& lw, float& st) {
  if (a < 16384)      { hw = a;         lw = 7; st = 8.f;  }
  else if (a < 20480) { hw = a - 16384; lw = 6; st = 16.f; }
  else                { hw = a - 20480; lw = 5; st = 32.f; }
}

// -------- fused decode + cost/iou/cand: per-(b,a) thread loops 20 gts --------
__global__ __launch_bounds__(256) void k_cost(
    const float* __restrict__ p3, const float* __restrict__ p4,
    const float* __restrict__ p5, const float* __restrict__ labels,
    float* __restrict__ dec, float* __restrict__ ious,
    float* __restrict__ cost, unsigned char* __restrict__ cand) {
  __shared__ float gt[NG][5];
  int tid = threadIdx.x, b = blockIdx.y;
  if (tid < NG * 5) ((float*)gt)[tid] = labels[b * NG * 5 + tid];
  __syncthreads();
  int a = blockIdx.x * 256 + tid;

  // ---- inline decode ----
  int hw, lw; float st;
  anchor_geom(a, hw, lw, st);
  const float* src; int HW;
  if (a < 16384)      { src = p3; HW = 16384; }
  else if (a < 20480) { src = p4; HW = 4096;  }
  else                { src = p5; HW = 1024;  }
  int x = hw & ((1 << lw) - 1), y = hw >> lw;
  const float* c0 = src + (size_t)b * 8 * HW + hw;
  float o0 = c0[0];
  float o1 = c0[(size_t)HW];
  float o2 = c0[(size_t)2 * HW];
  float o3 = c0[(size_t)3 * HW];
  float o4 = c0[(size_t)4 * HW];
  float o5 = c0[(size_t)5 * HW];
  float o6 = c0[(size_t)6 * HW];
  float o7 = c0[(size_t)7 * HW];
  float px = (o0 + (float)x) * st, py = (o1 + (float)y) * st;
  float pw = expf(o2) * st,        ph = expf(o3) * st;
  {
    float4* dst = (float4*)(dec + ((size_t)b * A_TOT + a) * 8);
    dst[0] = make_float4(px, py, pw, ph);
    dst[1] = make_float4(o4, o5, o6, o7);
  }

  float xc = ((float)x + 0.5f) * st, yc = ((float)y + 0.5f) * st;

  // per-anchor class-cost pieces: cls_cost(g) = -(cc[cg] + S)
  float so = sigf(o4);
  float cc0, cc1, cc2, S;
  {
    float q0 = sqrtf(sigf(o5) * so);
    float q1 = sqrtf(sigf(o6) * so);
    float q2 = sqrtf(sigf(o7) * so);
    float lg0 = logf(q0 + 1e-8f), lg1 = logf(q1 + 1e-8f), lg2 = logf(q2 + 1e-8f);
    float m0 = logf(1.f - q0 + 1e-8f), m1 = logf(1.f - q1 + 1e-8f), m2 = logf(1.f - q2 + 1e-8f);
    S = m0 + m1 + m2;
    cc0 = lg0 - m0; cc1 = lg1 - m1; cc2 = lg2 - m2;
  }

  float iouv[NG];
  unsigned bothMask = 0;
  bool anyBox = false, anyCtr = false;
  float hpw = pw * 0.5f, hph = ph * 0.5f;
  float plx = px - hpw, prx = px + hpw, pty = py - hph, pby = py + hph;
  float parea = pw * ph;
  float r = 2.5f * st;

#pragma unroll
  for (int g = 0; g < NG; ++g) {
    float gx = gt[g][0], gy = gt[g][1], gw = gt[g][2], gh = gt[g][3];
    float hgw = gw * 0.5f, hgh = gh * 0.5f;
    float glx = gx - hgw, grx = gx + hgw, gty = gy - hgh, gby = gy + hgh;
    bool ib = (xc > glx) && (xc < grx) && (yc > gty) && (yc < gby);
    bool ic = (xc > gx - r) && (xc < gx + r) && (yc > gy - r) && (yc < gy + r);
    anyBox |= ib; anyCtr |= ic;
    if (ib && ic) bothMask |= (1u << g);
    float tlx = fmaxf(glx, plx), brx = fminf(grx, prx);
    float tly = fmaxf(gty, pty), bry = fminf(gby, pby);
    float en = ((tlx < brx) && (tly < bry)) ? 1.f : 0.f;
    float ai = (brx - tlx) * (bry - tly) * en;
    float au = gw * gh + parea - ai;
    iouv[g] = ai / (au + 1e-16f);
  }
  bool cd = anyBox || anyCtr;
  cand[(size_t)b * A_TOT + a] = cd ? 1 : 0;

#pragma unroll
  for (int g = 0; g < NG; ++g) {
    float iv = cd ? iouv[g] : 0.f;
    int cg = (int)gt[g][4];
    float ccg = (cg == 0) ? cc0 : ((cg == 1) ? cc1 : cc2);
    float c = -(ccg + S) - 3.f * logf(iv + 1e-8f) +
              (((bothMask >> g) & 1u) ? 0.f : 100000.f);
    size_t idx = ((size_t)(b * NG + g)) * A_TOT + a;
    ious[idx] = iv;
    cost[idx] = cd ? c : 1e9f;
  }
}

// -------- per-(b,g,chunk): partial top-10 ious + bottom-10 (cost,idx) --------
__global__ __launch_bounds__(256) void k_topk_part(
    const float* __restrict__ ious, const float* __restrict__ cost,
    float* __restrict__ pV, float* __restrict__ pC, int* __restrict__ pI) {
  int s = blockIdx.x, g = blockIdx.y, b = blockIdx.z, tid = threadIdx.x;
  int row = b * NG + g;
  const float* iouRow  = ious + (size_t)row * A_TOT;
  const float* costRow = cost + (size_t)row * A_TOT;
  int lo = s * CHUNK, hi = lo + CHUNK;

  __shared__ float sV[256][11];
  __shared__ float sC[256][11];
  __shared__ int   sI[256][11];

  // per-thread top-10 iou over ~11 strided elements
  float tv[10];
#pragma unroll
  for (int j = 0; j < 10; ++j) tv[j] = -1e30f;
  for (int i = lo + tid; i < hi; i += 256) {
    float v = iouRow[i];
#pragma unroll
    for (int j = 0; j < 10; ++j)
      if (v > tv[j]) { float t = tv[j]; tv[j] = v; v = t; }
  }
#pragma unroll
  for (int j = 0; j < 10; ++j) sV[tid][j] = tv[j];
  sV[tid][10] = -1e30f;

  // per-thread bottom-10 (cost, global idx), lexicographic
  float tc[10]; int ti[10];
#pragma unroll
  for (int j = 0; j < 10; ++j) { tc[j] = FLT_MAX; ti[j] = 0x7fffffff; }
  for (int i = lo + tid; i < hi; i += 256) {
    float c = costRow[i]; int ii = i;
#pragma unroll
    for (int j = 0; j < 10; ++j) {
      bool lt = (c < tc[j]) || (c == tc[j] && ii < ti[j]);
      if (lt) {
        float t = tc[j]; tc[j] = c; c = t;
        int t2 = ti[j]; ti[j] = ii; ii = t2;
      }
    }
  }
#pragma unroll
  for (int j = 0; j < 10; ++j) { sC[tid][j] = tc[j]; sI[tid][j] = ti[j]; }
  sC[tid][10] = FLT_MAX; sI[tid][10] = 0x7fffffff;
  __syncthreads();

  for (int half = 128; half >= 1; half >>= 1) {
    if (tid < half) {
      { // iou merge (desc)
        const float* Ar = sV[tid];
        const float* Br = sV[tid + half];
        float out[10]; int pa = 0, pb = 0;
#pragma unroll
        for (int j = 0; j < 10; ++j) {
          float av = Ar[pa], bv = Br[pb];
          bool ta = (av >= bv);
          out[j] = ta ? av : bv;
          pa += ta ? 1 : 0; pb += ta ? 0 : 1;
        }
#pragma unroll
        for (int j = 0; j < 10; ++j) sV[tid][j] = out[j];
      }
      { // cost merge (asc, lexicographic)
        const float* Ac = sC[tid]; const float* Bc = sC[tid + half];
        const int*   Ai = sI[tid]; const int*   Bi = sI[tid + half];
        float oc[10]; int oi[10]; int pa = 0, pb = 0;
#pragma unroll
        for (int j = 0; j < 10; ++j) {
          float ac = Ac[pa], bc = Bc[pb];
          int ai_ = Ai[pa], bi_ = Bi[pb];
          bool ta = (ac < bc) || (ac == bc && ai_ < bi_);
          oc[j] = ta ? ac : bc; oi[j] = ta ? ai_ : bi_;
          pa += ta ? 1 : 0; pb += ta ? 0 : 1;
        }
#pragma unroll
        for (int j = 0; j < 10; ++j) { sC[tid][j] = oc[j]; sI[tid][j] = oi[j]; }
      }
    }
    __syncthreads();
  }

  if (tid < 10) {
    size_t base = ((size_t)row * SPLIT + s) * 10;
    pV[base + tid] = sV[0][tid];
    pC[base + tid] = sC[0][tid];
    pI[base + tid] = sI[0][tid];
  }
}

// -------- per-(b,g): merge 8x10 partials -> dyn_k + threshold (cost,idx) --------
__global__ __launch_bounds__(128) void k_topk_merge(
    const float* __restrict__ pV, const float* __restrict__ pC,
    const int* __restrict__ pI, float* __restrict__ thrC, int* __restrict__ thrI) {
  int g = blockIdx.x, b = blockIdx.y, tid = threadIdx.x;
  int row = b * NG + g;
  constexpr int NC = SPLIT * 10;   // 80 candidates
  __shared__ float sV[NC], sC[NC];
  __shared__ int   sI[NC];
  __shared__ float slot[10];
  __shared__ int kS;

  if (tid < NC) {
    size_t base = (size_t)row * NC + tid;
    sV[tid] = pV[base];
    sC[tid] = pC[base];
    sI[tid] = pI[base];
  }
  __syncthreads();

  float myV = 0.f, myC = 0.f; int myI = 0, rankV = 0;
  if (tid < NC) {
    myV = sV[tid]; myC = sC[tid]; myI = sI[tid];
    for (int j = 0; j < NC; ++j) {
      float v = sV[j];
      rankV += ((v > myV) || (v == myV && j < tid)) ? 1 : 0;
    }
  }
  if (tid < NC && rankV < 10) slot[rankV] = myV;   // ranks 0..9 all exist
  __syncthreads();
  if (tid == 0) {
    float sum = 0.f;
#pragma unroll
    for (int j = 0; j < 10; ++j) sum += slot[j];
    int k = (int)sum; if (k < 1) k = 1;            // dyn_k in [1,10]
    kS = k;
  }
  __syncthreads();
  if (tid < NC) {
    int rankC = 0;
    for (int j = 0; j < NC; ++j) {
      float c = sC[j];
      rankC += ((c < myC) || (c == myC && sI[j] < myI)) ? 1 : 0;
    }
    if (rankC == kS - 1) { thrC[row] = myC; thrI[row] = myI; }
  }
}

// -------- matching resolution + detection loss partials --------
__global__ __launch_bounds__(256) void k_match(
    const float* __restrict__ dec, const float* __restrict__ labels,
    const float* __restrict__ ious, const float* __restrict__ cost,
    const unsigned char* __restrict__ cand,
    const float* __restrict__ thrC, const int* __restrict__ thrI,
    float* __restrict__ pm) {
  __shared__ float gt[NG][5];
  __shared__ float tC[NG];
  __shared__ int   tI[NG];
  int tid = threadIdx.x, b = blockIdx.y;
  if (tid < NG * 5) ((float*)gt)[tid] = labels[b * NG * 5 + tid];
  if (tid >= 128 && tid < 128 + NG) tC[tid - 128] = thrC[b * NG + tid - 128];
  if (tid >= 160 && tid < 160 + NG) tI[tid - 160] = thrI[b * NG + tid - 160];
  __syncthreads();
  int a = blockIdx.x * 256 + tid;

  bool cd = cand[(size_t)b * A_TOT + a] != 0;
  int cnt = 0, firstg = -1, gmin = 0;
  float minc = FLT_MAX, pisum = 0.f, iou_gmin = 0.f;
#pragma unroll
  for (int g = 0; g < NG; ++g) {
    size_t idx = ((size_t)(b * NG + g)) * A_TOT + a;
    float c = cost[idx];
    float iv = ious[idx];
    if (c < minc) { minc = c; gmin = g; iou_gmin = iv; }   // first-argmin
    bool m = cd && ((c < tC[g]) || (c == tC[g] && a <= tI[g]));
    if (m) { cnt++; if (firstg < 0) firstg = g; pisum += iv; }
  }
  if (cnt > 1) { firstg = gmin; pisum = iou_gmin; }  // multi -> best only
  bool fg = cnt > 0;

  const float4* dp = (const float4*)(dec + ((size_t)b * A_TOT + a) * 8);
  float4 d0 = dp[0], d1 = dp[1];
  float l_obj = bcef(d1.x, fg ? 1.f : 0.f);
  float l_iou = 0.f, l_cls = 0.f, nfg = fg ? 1.f : 0.f;
  if (fg) {
    float gx = gt[firstg][0], gy = gt[firstg][1];
    float gw = gt[firstg][2], gh = gt[firstg][3];
    int cg = (int)gt[firstg][4];
    float px = d0.x, py = d0.y, pw = d0.z, ph = d0.w;
    float tlx = fmaxf(px - pw * 0.5f, gx - gw * 0.5f);
    float brx = fminf(px + pw * 0.5f, gx + gw * 0.5f);
    float tly = fmaxf(py - ph * 0.5f, gy - gh * 0.5f);
    float bry = fminf(py + ph * 0.5f, gy + gh * 0.5f);
    float en = ((tlx < brx) && (tly < bry)) ? 1.f : 0.f;
    float ai = (brx - tlx) * (bry - tly) * en;
    float au = pw * ph + gw * gh - ai;
    float iou = ai / (au + 1e-16f);
    l_iou = 1.f - iou * iou;
    l_cls  = bcef(d1.y, (cg == 0) ? pisum : 0.f);
    l_cls += bcef(d1.z, (cg == 1) ? pisum : 0.f);
    l_cls += bcef(d1.w, (cg == 2) ? pisum : 0.f);
  }

  __shared__ float scr[4][4];
  float vals[4] = { nfg, l_iou, l_obj, l_cls };
#pragma unroll
  for (int k = 0; k < 4; ++k) {
    float v = vals[k];
#pragma unroll
    for (int off = 32; off > 0; off >>= 1) v += __shfl_down(v, off, 64);
    if ((tid & 63) == 0) scr[tid >> 6][k] = v;
  }
  __syncthreads();
  if (tid == 0) {
    int bf = blockIdx.y * gridDim.x + blockIdx.x;
#pragma unroll
    for (int k = 0; k < 4; ++k)
      pm[(size_t)bf * 4 + k] = scr[0][k] + scr[1][k] + scr[2][k] + scr[3][k];
  }
}

// -------- mask loss: fused log-softmax CE + dice stats --------
__global__ __launch_bounds__(256) void k_mask(
    const float* __restrict__ mi, const int* __restrict__ ml,
    float* __restrict__ pk) {
  constexpr long long N4 = ((long long)NB * HW_M) / 4;
  float ce = 0.f, tp0 = 0, tp1 = 0, tp2 = 0;
  float ss0 = 0, ss1 = 0, ss2 = 0, c0 = 0, c1 = 0, c2 = 0;

  auto proc = [&](float v0, float v1, float v2, int l) {
    float m = fmaxf(v0, fmaxf(v1, v2));
    float e0 = expf(v0 - m), e1 = expf(v1 - m), e2 = expf(v2 - m);
    float sum = e0 + e1 + e2;
    float lse = m + logf(sum);
    float inv = 1.f / sum;
    float s0 = e0 * inv, s1 = e1 * inv, s2 = e2 * inv;
    ss0 += s0; ss1 += s1; ss2 += s2;
    if (l == 0)      { ce += v0 - lse; tp0 += s0; c0 += 1.f; }
    else if (l == 1) { ce += v1 - lse; tp1 += s1; c1 += 1.f; }
    else             { ce += v2 - lse; tp2 += s2; c2 += 1.f; }
  };

  long long stride = (long long)gridDim.x * blockDim.x;
  for (long long i4 = (long long)blockIdx.x * blockDim.x + threadIdx.x;
       i4 < N4; i4 += stride) {
    long long i = i4 * 4;
    int b  = (int)(i >> 20);
    int hw = (int)(i & (HW_M - 1));
    const float* base = mi + (size_t)b * 3 * HW_M + hw;
    float4 x0 = *(const float4*)(base);
    float4 x1 = *(const float4*)(base + HW_M);
    float4 x2 = *(const float4*)(base + 2 * HW_M);
    int4 lb = *(const int4*)(ml + i);
    proc(x0.x, x1.x, x2.x, lb.x);
    proc(x0.y, x1.y, x2.y, lb.y);
    proc(x0.z, x1.z, x2.z, lb.z);
    proc(x0.w, x1.w, x2.w, lb.w);
  }

  __shared__ float scr[4][10];
  float vals[10] = { ce, tp0, tp1, tp2, ss0, ss1, ss2, c0, c1, c2 };
#pragma unroll
  for (int k = 0; k < 10; ++k) {
    float v = vals[k];
#pragma unroll
    for (int off = 32; off > 0; off >>= 1) v += __shfl_down(v, off, 64);
    if ((threadIdx.x & 63) == 0) scr[threadIdx.x >> 6][k] = v;
  }
  __syncthreads();
  if (threadIdx.x == 0) {
#pragma unroll
    for (int k = 0; k < 10; ++k)
      pk[(size_t)blockIdx.x * 10 + k] = scr[0][k] + scr[1][k] + scr[2][k] + scr[3][k];
  }
}

// -------- final reduce + output --------
__device__ __forceinline__ float bsum256(float v, float* scr) {
#pragma unroll
  for (int off = 32; off > 0; off >>= 1) v += __shfl_down(v, off, 64);
  __syncthreads();
  if ((threadIdx.x & 63) == 0) scr[threadIdx.x >> 6] = v;
  __syncthreads();
  return scr[0] + scr[1] + scr[2] + scr[3];
}

__global__ __launch_bounds__(256) void k_final(
    const float* __restrict__ pm, const float* __restrict__ pk,
    float* __restrict__ out) {
  __shared__ float scr[4];
  int tid = threadIdx.x;
  float t0 = 0, t1 = 0, t2 = 0, t3 = 0;
  for (int r = tid; r < 672; r += 256) {
    t0 += pm[(size_t)r * 4 + 0];
    t1 += pm[(size_t)r * 4 + 1];
    t2 += pm[(size_t)r * 4 + 2];
    t3 += pm[(size_t)r * 4 + 3];
  }
  float u[10] = {0,0,0,0,0,0,0,0,0,0};
  for (int r = tid; r < 1024; r += 256) {
#pragma unroll
    for (int k = 0; k < 10; ++k) u[k] += pk[(size_t)r * 10 + k];
  }
  float S_nfg = bsum256(t0, scr);
  float S_iou = bsum256(t1, scr);
  float S_obj = bsum256(t2, scr);
  float S_cls = bsum256(t3, scr);
  float S_ce  = bsum256(u[0], scr);
  float S_tp0 = bsum256(u[1], scr);
  float S_tp1 = bsum256(u[2], scr);
  float S_tp2 = bsum256(u[3], scr);
  float S_ss0 = bsum256(u[4], scr);
  float S_ss1 = bsum256(u[5], scr);
  float S_ss2 = bsum256(u[6], scr);
  float S_c0  = bsum256(u[7], scr);
  float S_c1  = bsum256(u[8], scr);
  float S_c2  = bsum256(u[9], scr);

  if (tid == 0) {
    float nfg = fmaxf(S_nfg, 1.f);
    float o1 = 5.f * S_iou / nfg;
    float o2 = S_obj / nfg;
    float o3 = S_cls / nfg;
    float ce = -S_ce / (float)((long long)NB << 20);
    float tps[3] = { S_tp0, S_tp1, S_tp2 };
    float sss[3] = { S_ss0, S_ss1, S_ss2 };
    float cns[3] = { S_c0, S_c1, S_c2 };
    float ds = 0.f;
#pragma unroll
    for (int c = 0; c < 3; ++c) {
      float tp = tps[c];
      float fp = sss[c] - tp;
      float fn = cns[c] - tp;
      ds += (2.f * tp + 1e-5f) / (2.f * tp + fn + fp + 1e-5f);
    }
    float dice = 1.f - ds / 3.f;
    float o4 = ce + dice;
    out[0] = o1 + o2 + o3 + o4;
    out[1] = o1;
    out[2] = o2;
    out[3] = o3;
    out[4] = o4;
    out[5] = 0.f;
  }
}

extern "C" void kernel_launch(void* const* d_in, const int* in_sizes, int n_in,
                              void* d_out, int out_size, void* d_ws, size_t ws_size,
                              hipStream_t stream) {
  const float* p3     = (const float*)d_in[0];
  const float* p4     = (const float*)d_in[1];
  const float* p5     = (const float*)d_in[2];
  const float* mi     = (const float*)d_in[3];
  const float* labels = (const float*)d_in[4];
  // d_in[5] input_images: unused by the loss
  const int*   ml     = (const int*)d_in[6];
  // d_in[7] now_epoch: unused

  float* ws   = (float*)d_ws;
  float* dec  = ws + OFF_DEC;
  float* ious = ws + OFF_IOUS;
  float* cost = ws + OFF_COST;
  float* thrC = ws + OFF_THRC;
  int*   thrI = (int*)(ws + OFF_THRI);
  unsigned char* cand = (unsigned char*)(ws + OFF_CAND);
  float* pm   = ws + OFF_PM;
  float* pk   = ws + OFF_PK;
  float* pV   = ws + OFF_PV;
  float* pC   = ws + OFF_PC;
  int*   pI   = (int*)(ws + OFF_PI);
  float* out  = (float*)d_out;

  dim3 gA(A_TOT / 256, NB);   // 21504 = 84*256 exactly
  k_cost<<<gA, 256, 0, stream>>>(p3, p4, p5, labels, dec, ious, cost, cand);
  k_topk_part<<<dim3(SPLIT, NG, NB), 256, 0, stream>>>(ious, cost, pV, pC, pI);
  k_topk_merge<<<dim3(NG, NB), 128, 0, stream>>>(pV, pC, pI, thrC, thrI);
  k_match<<<gA, 256, 0, stream>>>(dec, labels, ious, cost, cand, thrC, thrI, pm);
  k_mask<<<1024, 256, 0, stream>>>(mi, ml, pk);
  k_final<<<1, 256, 0, stream>>>(pm, pk, out);
}